// Round 1
// baseline (498.658 us; speedup 1.0000x reference)
//
#include <hip/hip_runtime.h>
#include <cstdint>
#include <cstddef>

#define Bb 128
#define Tt 2048
#define Dd 512
#define Hh 512
#define Mtot (Bb*Tt)

typedef __attribute__((ext_vector_type(8))) _Float16 h8;
typedef __attribute__((ext_vector_type(4))) _Float16 h4v;
typedef __attribute__((ext_vector_type(4))) float f4;

// ---------------- kernel 1: W -> fp16 ----------------
__global__ void w16_kernel(const float* __restrict__ W, _Float16* __restrict__ W16) {
    int i = blockIdx.x * 256 + threadIdx.x;
    W16[i] = (_Float16)W[i];
}

// ---------------- kernel 2: col_t = relu(col @ W^T), fp32 exact ----------------
__global__ void col_proj_kernel(const float* __restrict__ col, const float* __restrict__ W,
                                float* __restrict__ colt) {
    __shared__ float c[Dd];
    int b = blockIdx.x;
    int tid = threadIdx.x;  // 128 threads
    for (int i = tid; i < Dd; i += 128) c[i] = col[b * Dd + i];
    __syncthreads();
    int h = blockIdx.y * 128 + tid;
    const f4* w4 = (const f4*)(W + (size_t)h * Dd);
    float acc = 0.f;
#pragma unroll 8
    for (int k = 0; k < Dd / 4; k++) {
        f4 w = w4[k];
        acc += w.x * c[4 * k] + w.y * c[4 * k + 1] + w.z * c[4 * k + 2] + w.w * c[4 * k + 3];
    }
    colt[b * Hh + h] = fmaxf(acc, 0.f);
}

// ---------------- kernel 3: fused scores GEMM ----------------
// scores[m] = mask[m] * sum_h colt[b][h] * relu( sum_k X[m][k] * W[h][k] )
// 2-pass fp16 split on X (x_hi + x_lo), W in fp16. 8 waves = 2(M) x 4(N).
// Wave tile 32x128, acc f32x4[2][8]. BK=32, K-steps=16.
__global__ __launch_bounds__(512) void scores_kernel(
    const float* __restrict__ X,        // [M][512]
    const _Float16* __restrict__ W16,   // [512][512]
    const float* __restrict__ colt,     // [128][512]
    const int* __restrict__ mask,       // [M]
    float* __restrict__ scores)         // [M]
{
    __shared__ _Float16 sW[512 * 32];    // 32KB, swizzled [row][kchunk^((row>>1)&3)]
    __shared__ _Float16 sXhi[64 * 32];   // 4KB
    __shared__ _Float16 sXlo[64 * 32];   // 4KB
    __shared__ float scolt[Hh];          // 2KB
    __shared__ float sred[4][64];        // 1KB

    const int tid = threadIdx.x;
    const int wg = blockIdx.x;
    const long m0 = (long)wg * 64;
    const int b = (int)(m0 >> 11);

    scolt[tid] = colt[b * Hh + tid];

    const int wave = tid >> 6;
    const int lane = tid & 63;
    const int wm = wave >> 2;   // 0..1
    const int wn = wave & 3;    // 0..3
    const int l16 = lane & 15;
    const int khi = lane >> 4;  // 0..3

    f4 acc[2][8];
#pragma unroll
    for (int i = 0; i < 2; i++)
#pragma unroll
        for (int j = 0; j < 8; j++) {
            f4 z = {0.f, 0.f, 0.f, 0.f};
            acc[i][j] = z;
        }

    const int xrow = tid >> 3;  // 0..63
    const int xf4  = tid & 7;   // float4 index within 32-float row slice

    for (int ks = 0; ks < 16; ks++) {
        const int k0 = ks * 32;
        __syncthreads();  // protect LDS from previous iteration's readers
        // ---- stage W: thread tid stages row `tid`, 64B = 4 x 16B chunks ----
        {
            const uint4* s4 = (const uint4*)(W16 + (size_t)tid * Dd + k0);
#pragma unroll
            for (int cc = 0; cc < 4; cc++) {
                uint4 v = s4[cc];
                int cs = cc ^ ((tid >> 1) & 3);
                *(uint4*)((char*)sW + tid * 64 + cs * 16) = v;
            }
        }
        // ---- stage X: float4 -> fp16 hi/lo split ----
        {
            const float4 xv = *(const float4*)(X + (m0 + xrow) * (size_t)Dd + k0 + xf4 * 4);
            float xs[4] = {xv.x, xv.y, xv.z, xv.w};
            _Float16 hi[4], lo[4];
#pragma unroll
            for (int j = 0; j < 4; j++) {
                hi[j] = (_Float16)xs[j];
                lo[j] = (_Float16)(xs[j] - (float)hi[j]);
            }
            int kc = xf4 >> 1;
            int kcs = kc ^ ((xrow >> 1) & 3);
            int byteoff = xrow * 64 + kcs * 16 + (xf4 & 1) * 8;
            *(h4v*)((char*)sXhi + byteoff) = *(h4v*)hi;
            *(h4v*)((char*)sXlo + byteoff) = *(h4v*)lo;
        }
        __syncthreads();

        // ---- fragment loads + MFMA ----
        h8 ahi[2], alo[2];
#pragma unroll
        for (int mr = 0; mr < 2; mr++) {
            int row = wm * 32 + mr * 16 + l16;
            int kb = (khi ^ ((row >> 1) & 3)) * 16;
            ahi[mr] = *(const h8*)((const char*)sXhi + row * 64 + kb);
            alo[mr] = *(const h8*)((const char*)sXlo + row * 64 + kb);
        }
#pragma unroll
        for (int nr = 0; nr < 8; nr++) {
            int row = wn * 128 + nr * 16 + l16;
            int kb = (khi ^ ((row >> 1) & 3)) * 16;
            h8 bf = *(const h8*)((const char*)sW + row * 64 + kb);
            acc[0][nr] = __builtin_amdgcn_mfma_f32_16x16x32_f16(ahi[0], bf, acc[0][nr], 0, 0, 0);
            acc[1][nr] = __builtin_amdgcn_mfma_f32_16x16x32_f16(ahi[1], bf, acc[1][nr], 0, 0, 0);
            acc[0][nr] = __builtin_amdgcn_mfma_f32_16x16x32_f16(alo[0], bf, acc[0][nr], 0, 0, 0);
            acc[1][nr] = __builtin_amdgcn_mfma_f32_16x16x32_f16(alo[1], bf, acc[1][nr], 0, 0, 0);
        }
    }

    // ---- epilogue: relu * colt, reduce over N ----
    float rs[2][4];
#pragma unroll
    for (int mr = 0; mr < 2; mr++)
#pragma unroll
        for (int r = 0; r < 4; r++) rs[mr][r] = 0.f;

#pragma unroll
    for (int nr = 0; nr < 8; nr++) {
        float cv = scolt[wn * 128 + nr * 16 + l16];
#pragma unroll
        for (int mr = 0; mr < 2; mr++)
#pragma unroll
            for (int r = 0; r < 4; r++)
                rs[mr][r] += fmaxf(acc[mr][nr][r], 0.f) * cv;
    }
    // reduce across the 16 columns (lanes differing in bits 0..3)
#pragma unroll
    for (int mr = 0; mr < 2; mr++)
#pragma unroll
        for (int r = 0; r < 4; r++) {
            float v = rs[mr][r];
            v += __shfl_xor(v, 1);
            v += __shfl_xor(v, 2);
            v += __shfl_xor(v, 4);
            v += __shfl_xor(v, 8);
            rs[mr][r] = v;
        }
    if (l16 == 0) {
#pragma unroll
        for (int mr = 0; mr < 2; mr++)
#pragma unroll
            for (int r = 0; r < 4; r++) {
                int row = wm * 32 + mr * 16 + (lane >> 4) * 4 + r;
                sred[wn][row] = rs[mr][r];   // unique writer per (wn,row): deterministic
            }
    }
    __syncthreads();
    if (tid < 64) {
        long m = m0 + tid;
        float s = sred[0][tid] + sred[1][tid] + sred[2][tid] + sred[3][tid];
        scores[m] = s * (float)mask[m];
    }
}

// ---------------- kernel 4: softmax per b + copy col into cat section ----------------
__global__ void softmax_kernel(const float* __restrict__ scores, const float* __restrict__ col,
                               float* __restrict__ attn, float* __restrict__ out) {
    __shared__ float sm[256];
    int b = blockIdx.x, tid = threadIdx.x;
    const float* srow = scores + (size_t)b * Tt;
    float mx = -1e30f;
#pragma unroll
    for (int i = 0; i < 8; i++) mx = fmaxf(mx, srow[tid + i * 256]);
    sm[tid] = mx;
    __syncthreads();
    for (int s = 128; s > 0; s >>= 1) {
        if (tid < s) sm[tid] = fmaxf(sm[tid], sm[tid + s]);
        __syncthreads();
    }
    float M = sm[0];
    __syncthreads();
    float e[8];
    float sum = 0.f;
#pragma unroll
    for (int i = 0; i < 8; i++) {
        e[i] = __expf(srow[tid + i * 256] - M);
        sum += e[i];
    }
    sm[tid] = sum;
    __syncthreads();
    for (int s = 128; s > 0; s >>= 1) {
        if (tid < s) sm[tid] += sm[tid + s];
        __syncthreads();
    }
    float inv = 1.f / sm[0];
    float* arow = attn + (size_t)b * Tt;
#pragma unroll
    for (int i = 0; i < 8; i++) arow[tid + i * 256] = e[i] * inv;
    // copy col_output into cat section: out[b*1024 + 0..511]
    for (int d = tid; d < Dd; d += 256) out[(size_t)b * 1024 + d] = col[(size_t)b * Dd + d];
}

// ---------------- kernel 5: partial weighted sums over t ----------------
__global__ void wsum_kernel(const float* __restrict__ attn, const float* __restrict__ X,
                            float* __restrict__ part) {
    int dh = blockIdx.x;   // 0..1
    int tc = blockIdx.y;   // 0..7
    int b  = blockIdx.z;   // 0..127
    int tid = threadIdx.x; // 256
    int d = dh * 256 + tid;
    __shared__ float sa[256];
    int t0 = tc * 256;
    sa[tid] = attn[(size_t)b * Tt + t0 + tid];
    __syncthreads();
    float acc = 0.f;
    const float* xp = X + ((size_t)b * Tt + t0) * Dd + d;
#pragma unroll 4
    for (int j = 0; j < 256; j++) acc += sa[j] * xp[(size_t)j * Dd];
    part[((size_t)b * 8 + tc) * Dd + d] = acc;
}

// ---------------- kernel 6: combine partials, write both outputs ----------------
__global__ void combine_kernel(const float* __restrict__ part, float* __restrict__ out) {
    int i = blockIdx.x * 256 + threadIdx.x;  // < 65536
    int b = i >> 9, d = i & 511;
    float s = 0.f;
#pragma unroll
    for (int tc = 0; tc < 8; tc++) s += part[((size_t)b * 8 + tc) * Dd + d];
    out[(size_t)b * 1024 + 512 + d] = s;                 // cat section, second half
    out[(size_t)Bb * 1024 + (size_t)b * 512 + d] = s;    // attention_output section
}

extern "C" void kernel_launch(void* const* d_in, const int* in_sizes, int n_in,
                              void* d_out, int out_size, void* d_ws, size_t ws_size,
                              hipStream_t stream) {
    const float* col  = (const float*)d_in[0];   // [128,512]
    const float* X    = (const float*)d_in[1];   // [128,2048,512]
    const int*   mask = (const int*)d_in[2];     // [128,2048]
    const float* W    = (const float*)d_in[3];   // [512,512]
    float* out = (float*)d_out;

    char* ws = (char*)d_ws;
    _Float16* W16   = (_Float16*)ws;                     // 512KB
    float*    colt  = (float*)(ws + (512 << 10));        // 256KB
    float*    scores= (float*)(ws + (768 << 10));        // 1MB
    float*    attn  = (float*)(ws + (1792 << 10));       // 1MB
    float*    part  = (float*)(ws + (2816 << 10));       // 2MB

    hipLaunchKernelGGL(w16_kernel, dim3(Hh * Dd / 256), dim3(256), 0, stream, W, W16);
    hipLaunchKernelGGL(col_proj_kernel, dim3(Bb, Hh / 128), dim3(128), 0, stream, col, W, colt);
    hipLaunchKernelGGL(scores_kernel, dim3(Mtot / 64), dim3(512), 0, stream,
                       X, W16, colt, mask, scores);
    hipLaunchKernelGGL(softmax_kernel, dim3(Bb), dim3(256), 0, stream, scores, col, attn, out);
    hipLaunchKernelGGL(wsum_kernel, dim3(2, 8, Bb), dim3(256), 0, stream, attn, X, part);
    hipLaunchKernelGGL(combine_kernel, dim3(65536 / 256), dim3(256), 0, stream, part, out);
}